// Round 2
// baseline (81.227 us; speedup 1.0000x reference)
//
#include <hip/hip_runtime.h>
#include <hip/hip_bf16.h>

#define B_ 128
#define I_ 2048
#define O_ 2048
#define SEG 10
#define BK 128
#define NST (I_ / BK)     // 16 steps
#define TILE_BYTES 32768  // 128 rows x 128 k x 2B (bf16), swizzled

typedef __attribute__((ext_vector_type(8))) short bf16x8;
typedef __attribute__((ext_vector_type(4))) float f32x4;

static __device__ __forceinline__ unsigned short f2bf(float f) {
    unsigned u = __float_as_uint(f);
    u += 0x7FFFu + ((u >> 16) & 1u);
    return (unsigned short)(u >> 16);
}

// ---------------------------------------------------------------------------
// Prepass: x [128][2048] f32  ->  xb: 16 tiles of [128 rows][128 k] bf16,
// XOR-swizzled so the main kernel's ds_read_b128 A-fragment loads are
// conflict-free: byte(row,kl) = row*256 + ((kl*2) ^ ((row&7)<<4))
// ---------------------------------------------------------------------------
__global__ void xconv(const float* __restrict__ x, char* __restrict__ xb) {
    int idx = blockIdx.x * 256 + threadIdx.x;   // 0 .. 32767 (chunks of 8 k)
    int row = idx >> 8;                         // 0..127
    int c   = idx & 255;                        // chunk within row
    int k0  = c * 8;
    int t   = k0 >> 7;
    int kl  = k0 & 127;

    const float* xp = x + (size_t)row * I_ + k0;
    float4 a = *reinterpret_cast<const float4*>(xp);
    float4 b = *reinterpret_cast<const float4*>(xp + 4);

    bf16x8 h;
    h[0] = (short)f2bf(a.x); h[1] = (short)f2bf(a.y);
    h[2] = (short)f2bf(a.z); h[3] = (short)f2bf(a.w);
    h[4] = (short)f2bf(b.x); h[5] = (short)f2bf(b.y);
    h[6] = (short)f2bf(b.z); h[7] = (short)f2bf(b.w);

    int sw = (row & 7) << 4;
    size_t off = (size_t)t * TILE_BYTES + row * 256 + ((kl * 2) ^ sw);
    *reinterpret_cast<bf16x8*>(xb + off) = h;
}

// ---------------------------------------------------------------------------
// Main fused kernel: 4 waves/block, one output column o per wave.
// MFMA N-tile: cols 0..9 = dendrite segments, col 10 = gated weight, 11..15 = 0
// ---------------------------------------------------------------------------
__global__ __launch_bounds__(256, 2) void neuro_fused(
    const char*  __restrict__ xb,     // swizzled bf16 x tiles
    const float* __restrict__ ctx,    // [O_]
    const float* __restrict__ w,      // [O_, I_]
    const float* __restrict__ bias,   // [O_]
    const float* __restrict__ astro,  // [O_]
    const float* __restrict__ D,      // [O_, I_, SEG]
    float* __restrict__ out)          // [B_, O_]
{
    __shared__ __align__(16) char xs[2][TILE_BYTES];   // 64 KiB double buffer

    const int tid  = threadIdx.x;
    const int wave = tid >> 6;
    const int lane = tid & 63;
    const int o    = blockIdx.x * 4 + wave;
    const int col  = lane & 15;   // MFMA n-index
    const int g    = lane >> 4;   // 16-lane group (k-group)

    const float* dptr;
    int dstride;
    float dmask;
    if (col < 10) {
        dptr = D + (size_t)o * (I_ * SEG) + col;
        dstride = SEG;
        dmask = 1.0f;
    } else {
        dptr = w + (size_t)o * I_;
        dstride = 1;
        dmask = (col == 10) ? 1.0f : 0.0f;
    }

    f32x4 acc[8];
#pragma unroll
    for (int m = 0; m < 8; ++m) acc[m] = (f32x4){0.f, 0.f, 0.f, 0.f};

    float am = astro[o] * ctx[o];
    am = 1.0f / (1.0f + __expf(-am));
    const float bo = bias[o];

    // --- stage x tile t into LDS buf via global_load_lds (16 B / lane) ------
    const int woff_base = wave * 1024;  // per-wave uniform
    auto stage = [&](int t, int buf) {
        const char* src = xb + (size_t)t * TILE_BYTES;
#pragma unroll
        for (int c = 0; c < 8; ++c) {
            int off = woff_base + c * 4096;
            __builtin_amdgcn_global_load_lds(
                (const __attribute__((address_space(1))) unsigned*)(src + off + lane * 16),
                (__attribute__((address_space(3))) unsigned*)(&xs[buf][0] + off),
                16, 0, 0);
        }
    };

    // --- D fragment prefetch for step t: k = t*128 + kk*32 + 8g + e ---------
    auto load_d = [&](int t, float* dr) {
        const float* p = dptr + (size_t)(t * BK + 8 * g) * dstride;
#pragma unroll
        for (int kk = 0; kk < 4; ++kk)
#pragma unroll
            for (int e = 0; e < 8; ++e)
                dr[kk * 8 + e] = p[(kk * 32 + e) * dstride];
    };

    // --- 32 MFMA on one staged tile -----------------------------------------
    const int sw = (col & 7) << 4;
    auto compute = [&](const float* dr, const char* base) {
#pragma unroll
        for (int kk = 0; kk < 4; ++kk) {
            bf16x8 bfrag;
#pragma unroll
            for (int e = 0; e < 8; ++e) bfrag[e] = (short)f2bf(dr[kk * 8 + e] * dmask);
            const int kswz = (kk * 64 + 16 * g) ^ sw;
#pragma unroll
            for (int m = 0; m < 8; ++m) {
                const char* ap = base + col * 256 + m * 4096 + kswz;
                bf16x8 afrag = *reinterpret_cast<const bf16x8*>(ap);
                acc[m] = __builtin_amdgcn_mfma_f32_16x16x32_bf16(afrag, bfrag, acc[m], 0, 0, 0);
            }
        }
    };
    // -------------------------------------------------------------------------

    float drA[32], drB[32];
    stage(0, 0);
    load_d(0, drA);
    __syncthreads();   // compiler drains vmcnt before barrier -> buf0 ready

#pragma unroll 1
    for (int t = 0; t < NST; t += 2) {
        stage(t + 1, 1);           // t+1 <= 15 always
        load_d(t + 1, drB);
        compute(drA, (const char*)xs[0]);
        __syncthreads();

        if (t + 2 < NST) {
            stage(t + 2, 0);
            load_d(t + 2, drA);
        }
        compute(drB, (const char*)xs[1]);
        __syncthreads();
    }

    // --- epilogue: lane holds C[b = m*16 + g*4 + r][col] ---------------------
#pragma unroll
    for (int m = 0; m < 8; ++m) {
#pragma unroll
        for (int r = 0; r < 4; ++r) {
            float v = acc[m][r];
            float dend = (col < 10) ? fmaxf(v, 0.0f) : 0.0f;
#pragma unroll
            for (int s = 1; s < 16; s <<= 1)
                dend += __shfl_xor(dend, s, 64);
            float lin = __shfl(v, (lane & 48) | 10, 64);
            if (col == 0) {
                int b = m * 16 + g * 4 + r;
                out[(size_t)b * O_ + o] = dend + am * lin + bo;
            }
        }
    }
}

extern "C" void kernel_launch(void* const* d_in, const int* in_sizes, int n_in,
                              void* d_out, int out_size, void* d_ws, size_t ws_size,
                              hipStream_t stream) {
    const float* x     = (const float*)d_in[0];
    const float* ctx   = (const float*)d_in[1];
    // d_in[2] = prev_activation (unused by the reference output)
    const float* w     = (const float*)d_in[3];
    const float* bias  = (const float*)d_in[4];
    const float* astro = (const float*)d_in[5];
    const float* D     = (const float*)d_in[6];
    float* out = (float*)d_out;
    char* xb = (char*)d_ws;   // 512 KiB

    xconv<<<dim3(128), dim3(256), 0, stream>>>(x, xb);
    neuro_fused<<<dim3(O_ / 4), dim3(256), 0, stream>>>(xb, ctx, w, bias, astro, D, out);
}

// Round 3
// 51.876 us; speedup vs baseline: 1.5658x; 1.5658x over previous
//
#include <hip/hip_runtime.h>
#include <hip/hip_bf16.h>

#define B_ 128
#define I_ 2048
#define O_ 2048
#define SEG 10
#define BK 64
#define NST (I_ / BK)      // 32 k-steps
#define XTILE 16384        // x tile: 128 rows x 64 k x 2B bf16, swizzled
#define DCH 2560           // D chunk: 64 i x 10 j x 4B f32, contiguous in D
#define DLS 2816           // + 256 B w chunk

typedef __attribute__((ext_vector_type(8))) short bf16x8;
typedef __attribute__((ext_vector_type(4))) float f32x4;

static __device__ __forceinline__ unsigned short f2bf(float f) {
    unsigned u = __float_as_uint(f);
    u += 0x7FFFu + ((u >> 16) & 1u);
    return (unsigned short)(u >> 16);
}

#define GLDS16(SRC, DST) \
    __builtin_amdgcn_global_load_lds( \
        (const __attribute__((address_space(1))) unsigned*)(SRC), \
        (__attribute__((address_space(3))) unsigned*)(DST), 16, 0, 0)
#define GLDS4(SRC, DST) \
    __builtin_amdgcn_global_load_lds( \
        (const __attribute__((address_space(1))) unsigned*)(SRC), \
        (__attribute__((address_space(3))) unsigned*)(DST), 4, 0, 0)

// ---------------------------------------------------------------------------
// Prepass: x [128][2048] f32 -> xb: 32 tiles of [128 rows][64 k] bf16,
// XOR-swizzled: byte(row,kl) = row*128 + ((kl*2) ^ ((row&7)<<4))
// ---------------------------------------------------------------------------
__global__ void xconv(const float* __restrict__ x, char* __restrict__ xb) {
    int idx = blockIdx.x * 256 + threadIdx.x;   // 0..32767, 8-k chunks
    int row = idx >> 8;
    int c   = idx & 255;
    int k0  = c * 8;
    int t   = k0 >> 6;
    int kl  = k0 & 63;

    const float* xp = x + (size_t)row * I_ + k0;
    float4 a = *reinterpret_cast<const float4*>(xp);
    float4 b = *reinterpret_cast<const float4*>(xp + 4);

    bf16x8 h;
    h[0] = (short)f2bf(a.x); h[1] = (short)f2bf(a.y);
    h[2] = (short)f2bf(a.z); h[3] = (short)f2bf(a.w);
    h[4] = (short)f2bf(b.x); h[5] = (short)f2bf(b.y);
    h[6] = (short)f2bf(b.z); h[7] = (short)f2bf(b.w);

    size_t off = (size_t)t * XTILE + row * 128 + ((kl * 2) ^ ((row & 7) << 4));
    *reinterpret_cast<bf16x8*>(xb + off) = h;
}

// ---------------------------------------------------------------------------
// Main fused kernel: 4 waves/block, one output column o per wave.
// B-tile cols: 0..9 = dendrite segments, 10 = weight row, 11..15 = masked 0.
// D and w staged via coalesced global_load_lds; fragments built from LDS.
// ---------------------------------------------------------------------------
__global__ __launch_bounds__(256, 2) void neuro_fused(
    const char*  __restrict__ xb,     // swizzled bf16 x tiles
    const float* __restrict__ ctx,    // [O_]
    const float* __restrict__ w,      // [O_, I_]
    const float* __restrict__ bias,   // [O_]
    const float* __restrict__ astro,  // [O_]
    const float* __restrict__ D,      // [O_, I_, SEG]
    float* __restrict__ out)          // [B_, O_]
{
    __shared__ __align__(16) char xs[2][XTILE];     // 32 KiB
    __shared__ __align__(16) char dls[4][2][DLS];   // 22 KiB

    const int tid  = threadIdx.x;
    const int wave = tid >> 6;
    const int lane = tid & 63;
    const int o    = blockIdx.x * 4 + wave;
    const int col  = lane & 15;   // MFMA n-index
    const int g    = lane >> 4;   // k-group

    f32x4 acc[8];
#pragma unroll
    for (int m = 0; m < 8; ++m) acc[m] = (f32x4){0.f, 0.f, 0.f, 0.f};

    float am = astro[o] * ctx[o];
    am = 1.0f / (1.0f + __expf(-am));
    const float bo = bias[o];

    // per-lane fragment addressing within the staged chunk
    const int   fbase = (col < 10) ? col * 4 : DCH;   // w region at +2560
    const int   fstr  = (col < 10) ? 40 : 4;
    const float dmask = (col <= 10) ? 1.0f : 0.0f;
    const int   sw    = (col & 7) << 4;

    auto stage_x = [&](int t, int buf) {
        const char* src = xb + (size_t)t * XTILE + wave * 4096 + lane * 16;
        char* dst = &xs[buf][wave * 4096];
#pragma unroll
        for (int c = 0; c < 4; ++c)
            GLDS16(src + c * 1024, dst + c * 1024);
    };

    auto stage_d = [&](int t, int buf) {
        const char* srcD = (const char*)D + (size_t)o * (I_ * SEG * 4) + (size_t)t * DCH;
        char* dst = &dls[wave][buf][0];
#pragma unroll
        for (int c = 0; c < 2; ++c)
            GLDS16(srcD + c * 1024 + lane * 16, dst + c * 1024);
#pragma unroll
        for (int c = 0; c < 2; ++c)
            GLDS4(srcD + 2048 + c * 256 + lane * 4, dst + 2048 + c * 256);
        const char* srcW = (const char*)w + (size_t)o * (I_ * 4) + t * (BK * 4);
        GLDS4(srcW + lane * 4, dst + DCH);
    };

    auto compute = [&](int buf) {
        const char* dbase = &dls[wave][buf][0];
        const char* xbase = &xs[buf][0];
#pragma unroll
        for (int kk = 0; kk < 2; ++kk) {
            const char* fp = dbase + fbase + (32 * kk + 8 * g) * fstr;
            bf16x8 bfrag;
#pragma unroll
            for (int e = 0; e < 8; ++e) {
                float v = *reinterpret_cast<const float*>(fp + e * fstr);
                bfrag[e] = (short)f2bf(v * dmask);
            }
            const int kswz = (64 * kk + 16 * g) ^ sw;
#pragma unroll
            for (int m = 0; m < 8; ++m) {
                bf16x8 afrag = *reinterpret_cast<const bf16x8*>(
                    xbase + (m * 16 + col) * 128 + kswz);
                acc[m] = __builtin_amdgcn_mfma_f32_16x16x32_bf16(afrag, bfrag, acc[m], 0, 0, 0);
            }
        }
    };

    stage_x(0, 0);
    stage_d(0, 0);
    __syncthreads();   // vmcnt(0) drain -> buf0 ready

#pragma unroll 1
    for (int t = 0; t < NST; t += 2) {
        stage_x(t + 1, 1);
        stage_d(t + 1, 1);
        compute(0);
        __syncthreads();

        if (t + 2 < NST) {
            stage_x(t + 2, 0);
            stage_d(t + 2, 0);
        }
        compute(1);
        __syncthreads();
    }

    // --- epilogue: lane holds C[b = m*16 + g*4 + r][col] ---------------------
#pragma unroll
    for (int m = 0; m < 8; ++m) {
#pragma unroll
        for (int r = 0; r < 4; ++r) {
            float v = acc[m][r];
            float dend = (col < 10) ? fmaxf(v, 0.0f) : 0.0f;
#pragma unroll
            for (int s = 1; s < 16; s <<= 1)
                dend += __shfl_xor(dend, s, 64);
            float lin = __shfl(v, (lane & 48) | 10, 64);
            if (col == 0) {
                int b = m * 16 + g * 4 + r;
                out[(size_t)b * O_ + o] = dend + am * lin + bo;
            }
        }
    }
}

extern "C" void kernel_launch(void* const* d_in, const int* in_sizes, int n_in,
                              void* d_out, int out_size, void* d_ws, size_t ws_size,
                              hipStream_t stream) {
    const float* x     = (const float*)d_in[0];
    const float* ctx   = (const float*)d_in[1];
    // d_in[2] = prev_activation (unused by the reference output)
    const float* w     = (const float*)d_in[3];
    const float* bias  = (const float*)d_in[4];
    const float* astro = (const float*)d_in[5];
    const float* D     = (const float*)d_in[6];
    float* out = (float*)d_out;
    char* xb = (char*)d_ws;   // 512 KiB swizzled bf16 x

    xconv<<<dim3(128), dim3(256), 0, stream>>>(x, xb);
    neuro_fused<<<dim3(O_ / 4), dim3(256), 0, stream>>>(xb, ctx, w, bias, astro, D, out);
}